// Round 10
// baseline (80.166 us; speedup 1.0000x reference)
//
#include <hip/hip_runtime.h>

#define NK 19
#define NB 8
#define NC 256
#define NP 8192           // 64*128
#define NBP (NB*NP)       // 65536

typedef unsigned char u8;
typedef __attribute__((ext_vector_type(8))) short bf16x8;   // 8 bf16 = 4 VGPR
typedef __attribute__((ext_vector_type(4))) float f32x4;    // MFMA C/D

// ---------------- kernel 1: argmax over classes + integer counts ----------------
__global__ __launch_bounds__(256) void k_argmax(const float* __restrict__ target,
                                                u8* __restrict__ lab,
                                                int* __restrict__ counts) {
  __shared__ float tl[256 * NK];                 // 19456 B
  __shared__ int lcnt[NK];
  if (threadIdx.x < NK) lcnt[threadIdx.x] = 0;
  const float4* src = (const float4*)(target + (size_t)blockIdx.x * (256 * NK));
  float4* dst = (float4*)tl;
  for (int i = threadIdx.x; i < 256 * NK / 4; i += 256) dst[i] = src[i];
  __syncthreads();
  const float* row = &tl[threadIdx.x * NK];
  float best = row[0]; int bk = 0;
#pragma unroll
  for (int k = 1; k < NK; ++k) { float v = row[k]; if (v > best) { best = v; bk = k; } }
  int g = blockIdx.x * 256 + threadIdx.x;
  lab[g] = (u8)bk;
  atomicAdd(&lcnt[bk], 1);
  __syncthreads();
  int b = g >> 13;
  if (threadIdx.x < NK) atomicAdd(&counts[b * NK + threadIdx.x], lcnt[threadIdx.x]);
}

// ---------------- kernel 2: class sums as MFMA GEMM (occupancy-fixed) ----------------
// sums[c][k] = sum_p feat[c][p]*onehot[p][k]; feat split hi/lo bf16 (truncate),
// onehot exact in bf16.  Fragment mapping identical to R9 (validated).
// Grid [f2][b8][q4][chunk16] = 1024 blocks x 4 waves; 2-deep named-slot pipeline.
__global__ __launch_bounds__(256, 6) void k_gemm(const float* __restrict__ fS,
                                                 const float* __restrict__ fT,
                                                 const u8* __restrict__ lab,
                                                 float* __restrict__ gpart) {
  int id = blockIdx.x;                           // [0, 1024)
  int chunk = id & 15;
  int q  = (id >> 4) & 3;
  int b  = (id >> 6) & 7;
  int f  = id >> 9;
  int t = threadIdx.x, wave = t >> 6, lane = t & 63;
  int row = lane & 15, kg = lane >> 4;
  const float* F = (f ? fT : fS) + (size_t)b * NC * NP;
  int c = q * 64 + wave * 16 + row;
  const float* rp = F + (size_t)c * NP;
  const u8* lb = lab + b * NP;
  int pb = chunk * 512 + kg * 8;                 // lane's first pixel
  f32x4 acc0 = {0.f, 0.f, 0.f, 0.f};            // classes 0..15
  f32x4 acc1 = {0.f, 0.f, 0.f, 0.f};            // classes 16..18
  // 2-deep pipeline, named slots (no runtime-indexed arrays -> stays in VGPRs)
  float4 A0_0, A1_0, A0_1, A1_1; uint2 L_0, L_1;
  A0_0 = *(const float4*)(rp + pb);      A1_0 = *(const float4*)(rp + pb + 4);
  L_0  = *(const uint2*)(lb + pb);
  A0_1 = *(const float4*)(rp + pb + 32); A1_1 = *(const float4*)(rp + pb + 36);
  L_1  = *(const uint2*)(lb + pb + 32);

#define BODY(cA0, cA1, cL)                                                        \
  {                                                                               \
    union { bf16x8 v; unsigned u[4]; } ah, al, b0f, b1f;                          \
    float ax[8] = {cA0.x, cA0.y, cA0.z, cA0.w, cA1.x, cA1.y, cA1.z, cA1.w};       \
    _Pragma("unroll")                                                             \
    for (int jj = 0; jj < 4; ++jj) {                                              \
      float e0 = ax[2 * jj], e1 = ax[2 * jj + 1];                                 \
      ah.u[jj] = __builtin_amdgcn_perm(__float_as_uint(e1), __float_as_uint(e0),  \
                                       0x07060302u);                              \
      float t0 = e0 - __uint_as_float(__float_as_uint(e0) & 0xffff0000u);         \
      float t1 = e1 - __uint_as_float(__float_as_uint(e1) & 0xffff0000u);         \
      al.u[jj] = __builtin_amdgcn_perm(__float_as_uint(t1), __float_as_uint(t0),  \
                                       0x07060302u);                              \
    }                                                                             \
    unsigned lw0 = cL.x, lw1 = cL.y;                                              \
    int lj[8] = {(int)(lw0 & 255u), (int)((lw0 >> 8) & 255u),                     \
                 (int)((lw0 >> 16) & 255u), (int)(lw0 >> 24),                     \
                 (int)(lw1 & 255u), (int)((lw1 >> 8) & 255u),                     \
                 (int)((lw1 >> 16) & 255u), (int)(lw1 >> 24)};                    \
    _Pragma("unroll")                                                             \
    for (int jj = 0; jj < 4; ++jj) {                                              \
      b0f.u[jj] = (lj[2*jj] == row      ? 0x3F80u : 0u) |                         \
                  (lj[2*jj+1] == row    ? 0x3F800000u : 0u);                      \
      b1f.u[jj] = (lj[2*jj] == row + 16 ? 0x3F80u : 0u) |                         \
                  (lj[2*jj+1] == row+16 ? 0x3F800000u : 0u);                      \
    }                                                                             \
    acc0 = __builtin_amdgcn_mfma_f32_16x16x32_bf16(ah.v, b0f.v, acc0, 0, 0, 0);   \
    acc0 = __builtin_amdgcn_mfma_f32_16x16x32_bf16(al.v, b0f.v, acc0, 0, 0, 0);   \
    acc1 = __builtin_amdgcn_mfma_f32_16x16x32_bf16(ah.v, b1f.v, acc1, 0, 0, 0);   \
    acc1 = __builtin_amdgcn_mfma_f32_16x16x32_bf16(al.v, b1f.v, acc1, 0, 0, 0);   \
  }

#pragma unroll
  for (int i = 0; i < 8; ++i) {
    {
      float4 cA0 = A0_0, cA1 = A1_0; uint2 cL = L_0;
      if (i < 7) {
        int p = pb + (2 * i + 2) * 32;
        A0_0 = *(const float4*)(rp + p); A1_0 = *(const float4*)(rp + p + 4);
        L_0  = *(const uint2*)(lb + p);
      }
      BODY(cA0, cA1, cL)
    }
    {
      float4 cA0 = A0_1, cA1 = A1_1; uint2 cL = L_1;
      if (i < 7) {
        int p = pb + (2 * i + 3) * 32;
        A0_1 = *(const float4*)(rp + p); A1_1 = *(const float4*)(rp + p + 4);
        L_1  = *(const uint2*)(lb + p);
      }
      BODY(cA0, cA1, cL)
    }
  }
#undef BODY
  // writeback: D lane l holds D[(l>>4)*4 + r][l&15]
  int fbq = (f * NB + b) * 4 + q;
  float* outp = gpart + ((size_t)fbq * 16 + chunk) * 1216;   // 64 ch x 19
  int clocal = wave * 16 + kg * 4;
#pragma unroll
  for (int r = 0; r < 4; ++r) {
    outp[(clocal + r) * 19 + row] = acc0[r];
    if (row < 3) outp[(clocal + r) * 19 + 16 + row] = acc1[r];
  }
}

// ---------------- kernel 2b: fold the 16 K-chunks ----------------
__global__ __launch_bounds__(256) void k_sumred(const float* __restrict__ gpart,
                                                float* __restrict__ sums) {
  int fbq = blockIdx.x;                          // [0, 64)
  const float* src = gpart + (size_t)fbq * 16 * 1216;
  for (int idx = threadIdx.x; idx < 1216; idx += 256) {
    float s = 0.f;
#pragma unroll
    for (int ch = 0; ch < 16; ++ch) s += src[ch * 1216 + idx];
    sums[(size_t)fbq * 1216 + idx] = s;          // == [f][b][c][k] flat
  }
}

// ---------------- kernel 3: means + per-(f,b,k) center norms ----------------
__global__ __launch_bounds__(256) void k_means(const float* __restrict__ sums,
                                               const int* __restrict__ counts,
                                               float* __restrict__ means,
                                               float* __restrict__ cnorm) {
  int b = blockIdx.x / NK, k = blockIdx.x % NK;
  int c = threadIdx.x;
  float cnt = (float)counts[b * NK + k] + 1e-6f;
  size_t iS = ((size_t)(b * NC + c)) * NK + k;
  size_t iT = ((size_t)((NB + b) * NC + c)) * NK + k;
  float mS = sums[iS] / cnt;
  float mT = sums[iT] / cnt;
  means[iS] = mS;
  means[iT] = mT;
  float sS = mS * mS, sT = mT * mT;
#pragma unroll
  for (int off = 32; off > 0; off >>= 1) { sS += __shfl_down(sS, off, 64); sT += __shfl_down(sT, off, 64); }
  __shared__ float redS[4], redT[4];
  int wid = threadIdx.x >> 6, lane = threadIdx.x & 63;
  if (lane == 0) { redS[wid] = sS; redT[wid] = sT; }
  __syncthreads();
  if (threadIdx.x == 0) {
    float tS = redS[0] + redS[1] + redS[2] + redS[3];
    float tT = redT[0] + redT[1] + redT[2] + redT[3];
    cnorm[b * NK + k]           = fmaxf(sqrtf(tS), 1e-8f);
    cnorm[NB * NK + b * NK + k] = fmaxf(sqrtf(tT), 1e-8f);
  }
}

// ---------------- kernel 4: per-pixel cosine + squared diff (4-way channel split) ----------------
__global__ __launch_bounds__(256) void k_cos(const float* __restrict__ fS,
                                             const float* __restrict__ fT,
                                             const u8* __restrict__ lab,
                                             const float* __restrict__ means,
                                             const float* __restrict__ cnorm,
                                             float* __restrict__ partial) {
  __shared__ float R[1024];
  int b = blockIdx.x >> 7, pt = blockIdx.x & 127;
  int t = threadIdx.x;
  int px = t & 63, cg = t >> 6;
  int p = pt * 64 + px;
  int k = lab[b * NP + p];
  const float* rs = fS + (size_t)b * NC * NP + p;
  const float* rt = fT + (size_t)b * NC * NP + p;
  const float* mSb = means + (size_t)(b * NC) * NK;
  const float* mTb = means + (size_t)((NB + b) * NC) * NK;
  float dS = 0.f, nS = 0.f, dT = 0.f, nT = 0.f;
  int c0 = cg * 64;
#pragma unroll 8
  for (int j = 0; j < 64; ++j) {
    int c = c0 + j;
    float vS = rs[(size_t)c * NP];
    float vT = rt[(size_t)c * NP];
    float cS = mSb[c * NK + k];
    float cT = mTb[c * NK + k];
    dS += vS * cS; nS += vS * vS;
    dT += vT * cT; nT += vT * vT;
  }
  R[t] = dS; R[256 + t] = nS; R[512 + t] = dT; R[768 + t] = nT;
  __syncthreads();
  if (t < 64) {
    dS = R[t]       + R[64 + t]  + R[128 + t] + R[192 + t];
    nS = R[256 + t] + R[320 + t] + R[384 + t] + R[448 + t];
    dT = R[512 + t] + R[576 + t] + R[640 + t] + R[704 + t];
    nT = R[768 + t] + R[832 + t] + R[896 + t] + R[960 + t];
    float cnS = cnorm[b * NK + k];
    float cnT = cnorm[NB * NK + b * NK + k];
    float cosS = dS / (fmaxf(sqrtf(nS), 1e-8f) * cnS);
    float cosT = dT / (fmaxf(sqrtf(nT), 1e-8f) * cnT);
    float d = cosS - cosT;
    float v = d * d;
#pragma unroll
    for (int off = 32; off > 0; off >>= 1) v += __shfl_down(v, off, 64);
    if (px == 0) partial[blockIdx.x] = v;
  }
}

// ---------------- kernel 5: final deterministic reduction (1024 partials) ----------------
__global__ __launch_bounds__(256) void k_final(const float* __restrict__ partial,
                                               float* __restrict__ out) {
  int t = threadIdx.x;
  float v = partial[t] + partial[256 + t] + partial[512 + t] + partial[768 + t];
#pragma unroll
  for (int off = 32; off > 0; off >>= 1) v += __shfl_down(v, off, 64);
  __shared__ float red[4];
  int wid = t >> 6, lane = t & 63;
  if (lane == 0) red[wid] = v;
  __syncthreads();
  if (t == 0) out[0] = (red[0] + red[1] + red[2] + red[3]) * (1.0f / (float)NBP);
}

// ---------------- launch ----------------
extern "C" void kernel_launch(void* const* d_in, const int* in_sizes, int n_in,
                              void* d_out, int out_size, void* d_ws, size_t ws_size,
                              hipStream_t stream) {
  const float* fS     = (const float*)d_in[0];
  const float* fT     = (const float*)d_in[1];
  const float* target = (const float*)d_in[2];
  char* ws = (char*)d_ws;
  u8*    lab     = (u8*)   (ws + 0);        // 65536
  int*   counts  = (int*)  (ws + 65536);    // pad to 66560
  float* sums    = (float*)(ws + 66560);    // 311296 -> 377856
  float* means   = (float*)(ws + 377856);   // 311296 -> 689152
  float* cnorm   = (float*)(ws + 689152);   // pad to 690432
  float* partial = (float*)(ws + 690432);   // 4096 -> 694528
  float* gpart   = (float*)(ws + 694528);   // 64*16*1216*4 = 4980736
  float* out = (float*)d_out;

  hipMemsetAsync(counts, 0, NB * NK * sizeof(int), stream);
  k_argmax<<<NBP / 256,   256, 0, stream>>>(target, lab, counts);
  k_gemm  <<<1024,        256, 0, stream>>>(fS, fT, lab, gpart);
  k_sumred<<<64,          256, 0, stream>>>(gpart, sums);
  k_means <<<NB * NK,     256, 0, stream>>>(sums, counts, means, cnorm);
  k_cos   <<<NB * (NP / 64), 256, 0, stream>>>(fS, fT, lab, means, cnorm, partial);
  k_final <<<1, 256, 0, stream>>>(partial, out);
}